// Round 15
// baseline (27.345 us; speedup 1.0000x reference)
//
#include <hip/hip_runtime.h>

#define C 32
#define H 192
#define W 192
#define HW (H*W)        // 36864
#define NPIX (HW*2)     // 73728
#define KK 7
#define TH 4            // out rows per block
#define TWc 8           // out cols per block
#define HR (TH+6)       // 10 halo rows
#define WC (TWc+6)      // 14 halo cols
#define HALO (HR*WC)    // 140 halo pixels
#define XP 66           // LDS ch-stride pad (64 -> 66, kills bank conflicts)
#define NB 1152         // 48 ht x 24 wt blocks

// ONE kernel, original op order: 7x7 pixconv on x (input halo - no cross-block dep!),
// then per-pixel 1x1 channel mix, then store. No intermediate global buffer.
__global__ __launch_bounds__(256) void fused(
    const float* __restrict__ x, const float* __restrict__ w1,
    const float* __restrict__ cw, const float* __restrict__ cb,
    float* __restrict__ out)
{
    __shared__ float x_l[HALO * XP];   // 36.96 KB  [halo_px][ch], ch = c*2+n
    __shared__ float u_l[32 * XP];     // 8.45 KB   [out_px][ch]  (conv result)

    const int b    = blockIdx.x;
    const int l    = (b & 7) * (NB / 8) + (b >> 3);   // bijective XCD swizzle
    const int ht   = l / 24, wt = l % 24;
    const int h0   = ht * TH, w0 = wt * TWc;
    const int tid  = threadIdx.x;
    const int wv   = __builtin_amdgcn_readfirstlane(tid >> 6);  // wave id (uniform)
    const int lane = tid & 63;

    // ---- stage: x halo tile -> LDS transposed [px][ch] (zero-fill OOB) ----
    const float2* x2 = reinterpret_cast<const float2*>(x);
#pragma unroll
    for (int k = 0; k < 18; ++k) {
        const int idx = k * 256 + tid;
        if (idx < C * HALO) {
            const int c  = idx / HALO;
            const int px = idx - c * HALO;
            const int pr = px / WC, pc = px - pr * WC;
            const int y  = h0 - 3 + pr;
            const int xc = w0 - 3 + pc;
            float2 v = make_float2(0.f, 0.f);
            if ((unsigned)y < (unsigned)H && (unsigned)xc < (unsigned)W)
                v = x2[(size_t)c * HW + y * W + xc];
            x_l[px * XP + 2 * c]     = v.x;
            x_l[px * XP + 2 * c + 1] = v.y;
        }
    }
    __syncthreads();

    // ---- conv: wave = out row r=wv (8 px), lane = ch  (R7-k2 pattern vs LDS) ----
    {
        const int r    = wv;
        const int hrow = h0 + r;
        float acc[8];
#pragma unroll
        for (int p = 0; p < 8; ++p) acc[p] = 0.f;
#pragma unroll
        for (int i = 0; i < KK; ++i) {
            float zw[WC];
#pragma unroll
            for (int k = 0; k < WC; ++k)
                zw[k] = x_l[((r + i) * WC + k) * XP + lane];   // conflict-free b32
            const float* wp = w1 + (size_t)i * KK * HW + (size_t)hrow * W + w0;  // uniform -> s_load
#pragma unroll
            for (int j = 0; j < KK; ++j) {
#pragma unroll
                for (int p = 0; p < 8; ++p)
                    acc[p] += wp[(size_t)j * HW + p] * zw[j + p];
            }
        }
#pragma unroll
        for (int p = 0; p < 8; ++p)
            u_l[(r * 8 + p) * XP + lane] = acc[p];
    }
    __syncthreads();

    // ---- mix: wave -> o-octet [8wv, 8wv+8), lane = (px, n) ----
    float* tr = x_l;                              // overlay; x_l no longer read
    {
        const int o0 = wv * 8;
        const int px = lane >> 1, n = lane & 1;
        float macc[8];
#pragma unroll
        for (int oo = 0; oo < 8; ++oo) macc[oo] = 0.f;
#pragma unroll
        for (int c = 0; c < C; ++c) {
            const float v = u_l[px * XP + 2 * c + n];          // 2-way broadcast (free)
#pragma unroll
            for (int oo = 0; oo < 8; ++oo)
                macc[oo] += cw[(o0 + oo) * C + c] * v;         // uniform -> s_load
        }
#pragma unroll
        for (int oo = 0; oo < 8; ++oo)
            tr[(o0 + oo) * 68 + lane] = macc[oo] + cb[o0 + oo];  // [o][px*2+n]
    }
    __syncthreads();

    // ---- store: thread = (o, r, half) -> 8 contiguous floats (32B) ----
    {
        const int o    = tid >> 3;
        const int r    = (tid >> 1) & 3;
        const int half = tid & 1;
        const float* s = &tr[o * 68 + r * 16 + half * 8];
        const float4 a = *reinterpret_cast<const float4*>(s);
        const float4 q = *reinterpret_cast<const float4*>(s + 4);
        float* op = out + (size_t)o * NPIX + ((size_t)(h0 + r) * W + w0 + half * 4) * 2;
        *reinterpret_cast<float4*>(op)     = a;
        *reinterpret_cast<float4*>(op + 4) = q;
    }
}

extern "C" void kernel_launch(void* const* d_in, const int* in_sizes, int n_in,
                              void* d_out, int out_size, void* d_ws, size_t ws_size,
                              hipStream_t stream) {
    const float* x  = (const float*)d_in[0];   // (C,H,W,2)
    const float* w1 = (const float*)d_in[1];   // (1,1,49,H,W)
    const float* cw = (const float*)d_in[2];   // (C_out, C_in)
    const float* cb = (const float*)d_in[3];   // (C,)
    float* out = (float*)d_out;                // (C,H,W,2)
    (void)d_ws; (void)ws_size;

    hipLaunchKernelGGL(fused, dim3(NB), dim3(256), 0, stream, x, w1, cw, cb, out);
}